// Round 9
// baseline (364.393 us; speedup 1.0000x reference)
//
#include <hip/hip_runtime.h>
#include <hip/hip_fp16.h>
#include <stdint.h>

// ---------------- problem constants ----------------
#define NROWS  16384      // B*S
#define DMODEL 2048
#define DIN    4096
#define NG     (NROWS*3)

// ---------------- workspace layout (bytes) ----------------
#define WS_CNT   0
#define WS_BF    256
#define WS_WF    512                       // W_fused EXPERT-MAJOR [3][4096] f32
#define WS_GUM   65536
#define WS_ROWL  262144                    // 16384 ints (compacted)
#define WS_SEGC2 327680                    // 64 counters, 128B stride (8KB)
#define WS_SEGC1 335872                    // 64 counters, 128B stride (8KB)
#define WS_RSEG  344064                    // 64 x 256 ints segment rowlists (64KB)
#define WS_WH    (1u<<20)                  // W^T fp16 [2048][4096], pre-swizzled
#define WS_ACOMP (WS_WH + (16u<<20))       // A fp16 [16384][4096] by COMPACT idx, pre-swizzled
#define WS_ACOMP_BYTES ((size_t)NROWS * DIN * 2)

typedef __attribute__((ext_vector_type(8))) _Float16 f16x8;
typedef __attribute__((ext_vector_type(4))) float f32x4;

#define THREEFRY_PARTITIONABLE 1

__device__ __forceinline__ void tf2x32(uint32_t k0, uint32_t k1,
                                       uint32_t x0, uint32_t x1,
                                       uint32_t& o0, uint32_t& o1) {
  uint32_t k2 = k0 ^ k1 ^ 0x1BD11BDAu;
  x0 += k0; x1 += k1;
#define TFR(r) { x0 += x1; x1 = (x1 << r) | (x1 >> (32 - r)); x1 ^= x0; }
  TFR(13) TFR(15) TFR(26) TFR(6)
  x0 += k1; x1 += k2 + 1u;
  TFR(17) TFR(29) TFR(16) TFR(24)
  x0 += k2; x1 += k0 + 2u;
  TFR(13) TFR(15) TFR(26) TFR(6)
  x0 += k0; x1 += k1 + 3u;
  TFR(17) TFR(29) TFR(16) TFR(24)
  x0 += k1; x1 += k2 + 4u;
  TFR(13) TFR(15) TFR(26) TFR(6)
  x0 += k2; x1 += k0 + 5u;
#undef TFR
  o0 = x0; o1 = x1;
}

// Gumbel noise + (merged) zeroing of atomic counters: blocks 0-3 zero the
// 16KB segc region (segc2 then segc1, contiguous), block 4 zeros cnt.
__global__ void k_gumbel(float* __restrict__ g, int* __restrict__ cnt,
                         int* __restrict__ segz) {
  const int t = threadIdx.x;
  if (blockIdx.x < 4) {
    int base = ((int)blockIdx.x << 10) + (t << 2);
#pragma unroll
    for (int i = 0; i < 4; ++i) segz[base + i] = 0;
  } else if (blockIdx.x == 4 && t < 8) {
    cnt[t] = 0;
  }
  int j = blockIdx.x * blockDim.x + t;
  if (j >= NG) return;
  uint32_t b0, b1, bits;
#if THREEFRY_PARTITIONABLE
  tf2x32(0u, 42u, 0u, (uint32_t)j, b0, b1);
  bits = b0 ^ b1;
#else
  const int half = NG / 2;
  if (j < half) { tf2x32(0u, 42u, (uint32_t)j, (uint32_t)(j + half), b0, b1); bits = b0; }
  else          { tf2x32(0u, 42u, (uint32_t)(j - half), (uint32_t)j, b0, b1); bits = b1; }
#endif
  float U = __uint_as_float((bits >> 9) | 0x3f800000u) - 1.0f;
  U = fmaxf(U, 1e-10f);
  U = fminf(U, 1.0f);
  g[j] = -logf(-logf(U));
}

// W_fused (expert-major): Wf[e*4096+k] = sum_d W_share[k][d]*W_router[d][e]
__global__ __launch_bounds__(256)
void k_wfused(const float* __restrict__ Ws, const float* __restrict__ bsh,
              const float* __restrict__ Wr, const float* __restrict__ br,
              float* __restrict__ Wf, float* __restrict__ bf) {
  const int k = blockIdx.x;
  const int t = threadIdx.x;
  const float* src = (k < DIN) ? (Ws + (size_t)k * DMODEL) : bsh;
  float4 x0 = *(const float4*)(src + t * 8);
  float4 x1 = *(const float4*)(src + t * 8 + 4);
  float xv[8] = {x0.x, x0.y, x0.z, x0.w, x1.x, x1.y, x1.z, x1.w};
  float4 w4[6];
  const float4* wp = (const float4*)(Wr + t * 24);
#pragma unroll
  for (int i = 0; i < 6; ++i) w4[i] = wp[i];
  const float* wfv = (const float*)w4;
  float z0 = 0.f, z1 = 0.f, z2 = 0.f;
#pragma unroll
  for (int jj = 0; jj < 8; ++jj) {
    z0 = fmaf(xv[jj], wfv[jj*3+0], z0);
    z1 = fmaf(xv[jj], wfv[jj*3+1], z1);
    z2 = fmaf(xv[jj], wfv[jj*3+2], z2);
  }
#pragma unroll
  for (int off = 32; off > 0; off >>= 1) {
    z0 += __shfl_down(z0, off, 64);
    z1 += __shfl_down(z1, off, 64);
    z2 += __shfl_down(z2, off, 64);
  }
  __shared__ float red[4][3];
  int lane = t & 63, wv = t >> 6;
  if (lane == 0) { red[wv][0] = z0; red[wv][1] = z1; red[wv][2] = z2; }
  __syncthreads();
  if (t == 0) {
    float s0 = red[0][0] + red[1][0] + red[2][0] + red[3][0];
    float s1 = red[0][1] + red[1][1] + red[2][1] + red[3][1];
    float s2 = red[0][2] + red[1][2] + red[2][2] + red[3][2];
    if (k < DIN) { Wf[k] = s0; Wf[4096 + k] = s1; Wf[8192 + k] = s2; }
    else { bf[0] = s0 + br[0]; bf[1] = s1 + br[1]; bf[2] = s2 + br[2]; }
  }
}

// ---------------- fp16 helpers (RNE) ----------------
__device__ __forceinline__ uint16_t f16b(float x) {
  return __half_as_ushort(__float2half(x));
}
__device__ __forceinline__ uint2 pack4h(float4 v) {
  return make_uint2((uint32_t)f16b(v.x) | ((uint32_t)f16b(v.y) << 16),
                    (uint32_t)f16b(v.z) | ((uint32_t)f16b(v.w) << 16));
}

// Transpose W_share [4096][2048] f32 -> Wh [2048][4096] fp16, pre-swizzled by
// n-row (chunk c stored at c ^ (n&7)) so linear global_load_lds yields the
// conflict-free LDS layout (rounds 2-8 proven).
__global__ __launch_bounds__(256)
void k_wsplit(const float* __restrict__ Ws, uint16_t* __restrict__ Wh) {
  const int kt = blockIdx.x;        // 64 k-tiles of 64
  const int nb = blockIdx.y;        // 32 n-tiles of 64
  const int k0 = kt << 6, n0 = nb << 6;
  __shared__ float T[64][65];
  const int t = threadIdx.x;
#pragma unroll
  for (int r = 0; r < 4; ++r) {
    int lin = r * 256 + t;
    int ki = lin >> 4;
    int nj = (lin & 15) << 2;
    float4 v = *(const float4*)(Ws + (size_t)(k0 + ki) * DMODEL + n0 + nj);
    T[ki][nj+0] = v.x; T[ki][nj+1] = v.y; T[ki][nj+2] = v.z; T[ki][nj+3] = v.w;
  }
  __syncthreads();
#pragma unroll
  for (int r = 0; r < 4; ++r) {
    int lin = r * 256 + t;
    int nl = lin >> 4;
    int k4 = (lin & 15) << 2;
    int ng = n0 + nl;
    int c = k4 >> 3, e0 = k4 & 7;
    float x0 = T[k4+0][nl], x1 = T[k4+1][nl], x2 = T[k4+2][nl], x3 = T[k4+3][nl];
    size_t off = ((size_t)ng << 12) + k0 + ((size_t)((c ^ (ng & 7)) << 3)) + e0;
    *(uint2*)(Wh + off) = make_uint2((uint32_t)f16b(x0) | ((uint32_t)f16b(x1) << 16),
                                     (uint32_t)f16b(x2) | ((uint32_t)f16b(x3) << 16));
  }
}

// Router: wave-per-row, weights streamed from L2, segment-local atomics
// (rounds 6-8 proven, unchanged).
__global__ __launch_bounds__(256)
void k_router(const float* __restrict__ a1, const float* __restrict__ a2,
              const float* __restrict__ Wf, const float* __restrict__ bf,
              const float* __restrict__ gum, float* __restrict__ out,
              int* __restrict__ segc1, int* __restrict__ segc2,
              int* __restrict__ rowl_seg) {
  const int t = threadIdx.x;
  const int lane = t & 63, w = t >> 6;
  const int row = (int)blockIdx.x * 4 + w;
  const float* pa = a1 + ((size_t)row << 11) + (lane << 2);
  const float* pb = a2 + ((size_t)row << 11) + (lane << 2);
  const float* w0 = Wf + (lane << 2);
  const float* w1 = Wf + 4096 + (lane << 2);
  const float* w2 = Wf + 8192 + (lane << 2);
  float z0 = 0.f, z1 = 0.f, z2 = 0.f;
#pragma unroll
  for (int c = 0; c < 8; ++c) {
    const int k = c << 8;
    float4 a = *(const float4*)(pa + k);
    float4 u0 = *(const float4*)(w0 + k);
    float4 u1 = *(const float4*)(w1 + k);
    float4 u2 = *(const float4*)(w2 + k);
    z0 = fmaf(a.x,u0.x,fmaf(a.y,u0.y,fmaf(a.z,u0.z,fmaf(a.w,u0.w,z0))));
    z1 = fmaf(a.x,u1.x,fmaf(a.y,u1.y,fmaf(a.z,u1.z,fmaf(a.w,u1.w,z1))));
    z2 = fmaf(a.x,u2.x,fmaf(a.y,u2.y,fmaf(a.z,u2.z,fmaf(a.w,u2.w,z2))));
    float4 b = *(const float4*)(pb + k);
    float4 v0 = *(const float4*)(w0 + 2048 + k);
    float4 v1 = *(const float4*)(w1 + 2048 + k);
    float4 v2 = *(const float4*)(w2 + 2048 + k);
    z0 = fmaf(b.x,v0.x,fmaf(b.y,v0.y,fmaf(b.z,v0.z,fmaf(b.w,v0.w,z0))));
    z1 = fmaf(b.x,v1.x,fmaf(b.y,v1.y,fmaf(b.z,v1.z,fmaf(b.w,v1.w,z1))));
    z2 = fmaf(b.x,v2.x,fmaf(b.y,v2.y,fmaf(b.z,v2.z,fmaf(b.w,v2.w,z2))));
  }
  // butterfly reduce (commutative per stage -> bitwise identical on all lanes)
#pragma unroll
  for (int m = 1; m < 64; m <<= 1) {
    z0 += __shfl_xor(z0, m, 64);
    z1 += __shfl_xor(z1, m, 64);
    z2 += __shfl_xor(z2, m, 64);
  }
  const float l0 = z0 + bf[0] + gum[row*3+0];
  const float l1 = z1 + bf[1] + gum[row*3+1];
  const float l2 = z2 + bf[2] + gum[row*3+2];
  int idx = 0; float m = l0;
  if (l1 > m) { m = l1; idx = 1; }
  if (l2 > m) { idx = 2; }

  if (lane == 0) {
    const int seg = row >> 8;
    if (idx == 1) {
      atomicAdd(segc1 + (seg << 5), 1);
    } else if (idx == 2) {
      int p = atomicAdd(segc2 + (seg << 5), 1);
      rowl_seg[(seg << 8) + p] = row;
    }
  }
  if (idx < 2) {
    const float* src = (idx == 0) ? pa : pb;
    float* po = out + ((size_t)row << 11) + (lane << 2);
#pragma unroll
    for (int c = 0; c < 8; ++c)
      *(float4*)(po + (c << 8)) = *(const float4*)(src + (c << 8));
  }
}

// Compact 64 segment lists -> rowl[0..M) + cnt[0..2]; (merged) losses.
__global__ __launch_bounds__(256)
void k_fixup(const int* __restrict__ segc1, const int* __restrict__ segc2,
             const int* __restrict__ rowl_seg, int* __restrict__ cnt,
             int* __restrict__ rowl, float* __restrict__ losses) {
  __shared__ int scnt[64], sstart[64];
  const int t = threadIdx.x;
  if (t < 64) scnt[t] = segc2[t << 5];
  __syncthreads();
  if (t == 0) {
    int acc = 0, s1 = 0;
#pragma unroll
    for (int g = 0; g < 64; ++g) { sstart[g] = acc; acc += scnt[g]; }
#pragma unroll
    for (int g = 0; g < 64; ++g) s1 += segc1[g << 5];
    cnt[2] = acc; cnt[1] = s1; cnt[0] = NROWS - acc - s1;
    // losses: p is exactly one-hot => entropy term exactly 0
    const float inv = 1.0f / (float)NROWS;
    float m0 = (float)(NROWS - acc - s1) * inv;
    float m1 = (float)s1 * inv;
    float m2 = (float)acc * inv;
    float lb = -(m0 * logf(m0 + 1e-8f) + m1 * logf(m1 + 1e-8f)
               + m2 * logf(m2 + 1e-8f));
    losses[0] = 0.0f;
    losses[1] = lb;
  }
  __syncthreads();
  for (int g = 0; g < 64; ++g) {
    int c = scnt[g], base = sstart[g];
    for (int i = t; i < c; i += 256) rowl[base + i] = rowl_seg[(g << 8) + i];
  }
}

// Compaction: Acomp[i] <- fp16(combined[rowl[i]]) pre-swizzled (round-7/8 proven).
__global__ __launch_bounds__(256)
void k_acomp(const float* __restrict__ a1, const float* __restrict__ a2,
             const int* __restrict__ cnt, const int* __restrict__ rowl,
             uint16_t* __restrict__ acomp) {
  const int t = threadIdx.x;
  const int lane = t & 63, w = t >> 6;
  const int i = (int)blockIdx.x * 4 + w;    // compact index
  if (i >= cnt[2]) return;
  const int row = rowl[i];
  const int psw = i & 7;
  uint16_t* ar = acomp + ((size_t)i << 12);
  const float* pa = a1 + ((size_t)row << 11);
  const float* pb = a2 + ((size_t)row << 11);
#pragma unroll
  for (int it = 0; it < 8; ++it) {
    int e = (it << 8) + (lane << 2);        // element index 0..2047
    float4 va = *(const float4*)(pa + e);
    float4 vb = *(const float4*)(pb + e);
    int g = e >> 6, c = (e >> 3) & 7, o = e & 7;
    int d = (g << 6) + ((c ^ psw) << 3) + o;
    *(uint2*)(ar + d) = pack4h(va);
    *(uint2*)(ar + 2048 + d) = pack4h(vb);
  }
}

// Single-product fp16 MFMA GEMM over selected rows: out[row] = A@Wh + b.
// 128x64 tile (BN halved vs round 8: 1376 working blocks -> ~5.4/CU so
// cross-block overlap hides the per-K-step barrier drain), BK=64, 4 waves
// (2 wm x 2 wn), mfma_f32_16x16x32_f16. LDS 24.6KB -> 6 blocks/CU.
template<int AMODE>
__global__ __launch_bounds__(256, 6)
void k_gemm_fp16(const float* __restrict__ a1, const float* __restrict__ a2,
                 const uint16_t* __restrict__ Acomp,
                 const uint16_t* __restrict__ Wh,
                 const float* __restrict__ bsh, const int* __restrict__ cnt,
                 const int* __restrict__ rowl, float* __restrict__ out) {
  const int M = cnt[2];
  const int nwg = (int)gridDim.x;          // 4096 = 128 mTiles * 32 bn
  const int mTiles = nwg >> 5;
  // m204 bijective XCD remap (nwg%8==0 -> q-split exact), bm-major decode
  int xcd = blockIdx.x & 7, rest = blockIdx.x >> 3;
  int q = nwg >> 3, r = nwg & 7;
  int swz = (xcd < r ? xcd * (q + 1) : r * (q + 1) + (xcd - r) * q) + rest;
  const int bm = swz % mTiles;
  const int bn = swz / mTiles;             // 0..31
  if (bm * 128 >= M) return;
  const int n0 = bn << 6;

  __shared__ uint16_t AS[128 * 64];        // 16 KB
  __shared__ uint16_t BhS[64 * 64];        // 8 KB
  __shared__ int rows[128];
  const int t = threadIdx.x;
  const int lane = t & 63, w = t >> 6;
  const int wm = w >> 1, wn = w & 1;
  if (t < 128) { int i = bm * 128 + t; rows[t] = (i < M) ? rowl[i] : -1; }
  __syncthreads();

  f32x4 acc[4][2];
#pragma unroll
  for (int fm = 0; fm < 4; ++fm)
#pragma unroll
    for (int fn = 0; fn < 2; ++fn) acc[fm][fn] = (f32x4){0.f, 0.f, 0.f, 0.f};
  float bias[2];
#pragma unroll
  for (int fn = 0; fn < 2; ++fn)
    bias[fn] = bsh[n0 + (wn << 5) + (fn << 4) + (lane & 15)];

  const size_t arow0 = ((size_t)(bm << 7)) << 12;   // (bm*128)*4096 elems

  for (int kt = 0; kt < 64; ++kt) {
    __syncthreads();                 // prior iter's LDS reads done
    // ---- B stage: 8KB via global_load_lds, linear dest (src pre-swizzled)
#pragma unroll
    for (int i = 0; i < 2; ++i) {
      int idx = (w << 7) + (i << 6) + lane;          // 16B-chunk index 0..511
      int nrow = idx >> 3, c = idx & 7;
      size_t goff = ((size_t)(n0 + nrow) << 12) + (kt << 6) + (c << 3);
      __builtin_amdgcn_global_load_lds(
          (const __attribute__((address_space(1))) void*)(Wh + goff),
          (__attribute__((address_space(3))) void*)((char*)BhS + (w << 11) + (i << 10)),
          16, 0, 0);
    }
    // ---- A stage: 16KB
    if (AMODE == 0) {
#pragma unroll
      for (int i = 0; i < 4; ++i) {
        int idx = (w << 8) + (i << 6) + lane;
        int m = idx >> 3, c = idx & 7;
        const uint16_t* src = Acomp + arow0 + (((size_t)m) << 12) + (kt << 6) + (c << 3);
        __builtin_amdgcn_global_load_lds(
            (const __attribute__((address_space(1))) void*)src,
            (__attribute__((address_space(3))) void*)((char*)AS + (w << 12) + (i << 10)),
            16, 0, 0);
      }
    } else {
#pragma unroll
      for (int i = 0; i < 4; ++i) {
        int idx = t + (i << 8);
        int m = idx >> 3, c = idx & 7;
        int row = rows[m];
        float4 v0 = make_float4(0.f,0.f,0.f,0.f), v1 = v0;
        if (row >= 0) {
          const float* s = (kt < 32)
              ? (a1 + (size_t)row * DMODEL + (kt << 6) + (c << 3))
              : (a2 + (size_t)row * DMODEL + ((kt - 32) << 6) + (c << 3));
          v0 = *(const float4*)s; v1 = *(const float4*)(s + 4);
        }
        uint32_t q0 = (uint32_t)f16b(v0.x) | ((uint32_t)f16b(v0.y) << 16);
        uint32_t q1 = (uint32_t)f16b(v0.z) | ((uint32_t)f16b(v0.w) << 16);
        uint32_t q2 = (uint32_t)f16b(v1.x) | ((uint32_t)f16b(v1.y) << 16);
        uint32_t q3 = (uint32_t)f16b(v1.z) | ((uint32_t)f16b(v1.w) << 16);
        *(uint4*)((char*)AS + m * 128 + ((c ^ (m & 7)) << 4)) = make_uint4(q0, q1, q2, q3);
      }
    }
    __syncthreads();                 // drain vmcnt (gload_lds) + lgkm (ds_write)
    // ---- compute: 2 k-slices x 4x2 frags
#pragma unroll
    for (int ks = 0; ks < 2; ++ks) {
      const int chb = (ks << 2) | (lane >> 4);
      f16x8 af[4];
#pragma unroll
      for (int fm = 0; fm < 4; ++fm) {
        int rm = (wm << 6) + (fm << 4) + (lane & 15);
        af[fm] = *(const f16x8*)((const char*)AS + rm * 128 + ((chb ^ (rm & 7)) << 4));
      }
#pragma unroll
      for (int fn = 0; fn < 2; ++fn) {
        int rn = (wn << 5) + (fn << 4) + (lane & 15);
        int sw = (chb ^ (rn & 7)) << 4;
        f16x8 bh = *(const f16x8*)((const char*)BhS + rn * 128 + sw);
#pragma unroll
        for (int fm = 0; fm < 4; ++fm)
          acc[fm][fn] = __builtin_amdgcn_mfma_f32_16x16x32_f16(af[fm], bh, acc[fm][fn], 0, 0, 0);
      }
    }
  }
  // epilogue: C/D layout col=lane&15, row=(lane>>4)*4+j
#pragma unroll
  for (int fm = 0; fm < 4; ++fm) {
    int rbase = (wm << 6) + (fm << 4) + ((lane >> 4) << 2);
#pragma unroll
    for (int j = 0; j < 4; ++j) {
      int row = rows[rbase + j];
      if (row < 0) continue;
      float* po = out + (size_t)row * DMODEL + n0 + (wn << 5) + (lane & 15);
#pragma unroll
      for (int fn = 0; fn < 2; ++fn)
        po[fn << 4] = acc[fm][fn][j] + bias[fn];
    }
  }
}

// fp32 fallback GEMM (only if ws too small for Wh)
#define BM 128
#define BN 128
#define BK 32
__global__ __launch_bounds__(256)
void k_gemm_f32(const float* __restrict__ a1, const float* __restrict__ a2,
                const float* __restrict__ Ws, const float* __restrict__ bsh,
                const int* __restrict__ cnt, const int* __restrict__ rowl,
                float* __restrict__ out) {
  const int M = cnt[2];
  const int bm = blockIdx.x;
  if (bm * BM >= M) return;
  const int bn = blockIdx.y;
  __shared__ float As[BK][132];
  __shared__ float Bs[BK][128];
  __shared__ int rows[BM];
  const int t = threadIdx.x;
  if (t < BM) {
    int i = bm * BM + t;
    rows[t] = (i < M) ? rowl[i] : -1;
  }
  __syncthreads();
  float acc[8][8];
#pragma unroll
  for (int i = 0; i < 8; ++i)
#pragma unroll
    for (int j = 0; j < 8; ++j) acc[i][j] = 0.f;
  const int tx = t & 15, ty = t >> 4;
  for (int k0 = 0; k0 < DIN; k0 += BK) {
    const float* Abase = (k0 < DMODEL) ? a1 : a2;
    const int kb = (k0 < DMODEL) ? k0 : (k0 - DMODEL);
    float4 av[4], bv4[4];
#pragma unroll
    for (int r = 0; r < 4; ++r) {
      int lin = r * 256 + t;
      int mi = lin >> 3;
      int ki = (lin & 7) << 2;
      int row = rows[mi];
      av[r] = (row >= 0) ? *(const float4*)(Abase + (size_t)row * DMODEL + kb + ki)
                         : make_float4(0.f, 0.f, 0.f, 0.f);
    }
#pragma unroll
    for (int r = 0; r < 4; ++r) {
      int lin = r * 256 + t;
      int ki = lin >> 5;
      int ni = (lin & 31) << 2;
      bv4[r] = *(const float4*)(Ws + (size_t)(k0 + ki) * DMODEL + bn * BN + ni);
    }
    __syncthreads();
#pragma unroll
    for (int r = 0; r < 4; ++r) {
      int lin = r * 256 + t;
      int mi = lin >> 3;
      int ki = (lin & 7) << 2;
      As[ki + 0][mi] = av[r].x;
      As[ki + 1][mi] = av[r].y;
      As[ki + 2][mi] = av[r].z;
      As[ki + 3][mi] = av[r].w;
      int k2 = lin >> 5;
      int ni = (lin & 31) << 2;
      *(float4*)(&Bs[k2][ni]) = bv4[r];
    }
    __syncthreads();
#pragma unroll
    for (int kk = 0; kk < BK; ++kk) {
      float4 aL = *(const float4*)(&As[kk][ty << 2]);
      float4 aH = *(const float4*)(&As[kk][64 + (ty << 2)]);
      float4 bL = *(const float4*)(&Bs[kk][tx << 2]);
      float4 bH = *(const float4*)(&Bs[kk][64 + (tx << 2)]);
      float am[8] = {aL.x, aL.y, aL.z, aL.w, aH.x, aH.y, aH.z, aH.w};
      float bb[8] = {bL.x, bL.y, bL.z, bL.w, bH.x, bH.y, bH.z, bH.w};
#pragma unroll
      for (int i = 0; i < 8; ++i)
#pragma unroll
        for (int j = 0; j < 8; ++j)
          acc[i][j] = fmaf(am[i], bb[j], acc[i][j]);
    }
  }
  float bias[8];
#pragma unroll
  for (int j = 0; j < 4; ++j) {
    bias[j]     = bsh[bn * BN + (tx << 2) + j];
    bias[4 + j] = bsh[bn * BN + 64 + (tx << 2) + j];
  }
#pragma unroll
  for (int i = 0; i < 8; ++i) {
    int m = (i < 4) ? ((ty << 2) + i) : (64 + (ty << 2) + (i - 4));
    int row = rows[m];
    if (row < 0) continue;
    float* po = out + (size_t)row * DMODEL + bn * BN;
    float4 v0 = make_float4(acc[i][0] + bias[0], acc[i][1] + bias[1],
                            acc[i][2] + bias[2], acc[i][3] + bias[3]);
    float4 v1 = make_float4(acc[i][4] + bias[4], acc[i][5] + bias[5],
                            acc[i][6] + bias[6], acc[i][7] + bias[7]);
    *(float4*)(po + (tx << 2)) = v0;
    *(float4*)(po + 64 + (tx << 2)) = v1;
  }
}

extern "C" void kernel_launch(void* const* d_in, const int* in_sizes, int n_in,
                              void* d_out, int out_size, void* d_ws, size_t ws_size,
                              hipStream_t stream) {
  const float* a1  = (const float*)d_in[0];
  const float* a2  = (const float*)d_in[1];
  const float* Ws  = (const float*)d_in[2];
  const float* bsh = (const float*)d_in[3];
  const float* Wr  = (const float*)d_in[4];
  const float* br  = (const float*)d_in[5];
  float* out = (float*)d_out;
  char* ws = (char*)d_ws;
  int*      cnt   = (int*)(ws + WS_CNT);
  float*    bf    = (float*)(ws + WS_BF);
  float*    Wf    = (float*)(ws + WS_WF);
  float*    gum   = (float*)(ws + WS_GUM);
  int*      rowl  = (int*)(ws + WS_ROWL);
  int*      segc2 = (int*)(ws + WS_SEGC2);
  int*      segc1 = (int*)(ws + WS_SEGC1);
  int*      rseg  = (int*)(ws + WS_RSEG);
  uint16_t* Wh    = (uint16_t*)(ws + WS_WH);
  uint16_t* Acomp = (uint16_t*)(ws + WS_ACOMP);
  float* losses = out + (size_t)NROWS * DMODEL;

  const bool fp16path = ws_size >= (size_t)WS_ACOMP;
  const bool fullA = ws_size >= (size_t)WS_ACOMP + WS_ACOMP_BYTES;

  hipLaunchKernelGGL(k_gumbel, dim3((NG + 255)/256), dim3(256), 0, stream, gum, cnt, segc2);
  hipLaunchKernelGGL(k_wfused, dim3(DIN + 1),        dim3(256), 0, stream, Ws, bsh, Wr, br, Wf, bf);
  if (fp16path) {
    hipLaunchKernelGGL(k_wsplit, dim3(64, 32),       dim3(256), 0, stream, Ws, Wh);
    hipLaunchKernelGGL(k_router, dim3(NROWS / 4),    dim3(256), 0, stream,
                       a1, a2, Wf, bf, gum, out, segc1, segc2, rseg);
    hipLaunchKernelGGL(k_fixup,  dim3(1),            dim3(256), 0, stream,
                       segc1, segc2, rseg, cnt, rowl, losses);
    if (fullA) {
      hipLaunchKernelGGL(k_acomp, dim3(NROWS / 4),   dim3(256), 0, stream,
                         a1, a2, cnt, rowl, Acomp);
      hipLaunchKernelGGL((k_gemm_fp16<0>), dim3((NROWS / 128) * 32), dim3(256), 0, stream,
                         a1, a2, Acomp, Wh, bsh, cnt, rowl, out);
    } else {
      hipLaunchKernelGGL((k_gemm_fp16<1>), dim3((NROWS / 128) * 32), dim3(256), 0, stream,
                         a1, a2, Acomp, Wh, bsh, cnt, rowl, out);
    }
  } else {
    hipLaunchKernelGGL(k_router, dim3(NROWS / 4),    dim3(256), 0, stream,
                       a1, a2, Wf, bf, gum, out, segc1, segc2, rseg);
    hipLaunchKernelGGL(k_fixup,  dim3(1),            dim3(256), 0, stream,
                       segc1, segc2, rseg, cnt, rowl, losses);
    hipLaunchKernelGGL(k_gemm_f32, dim3(NROWS / BM, DMODEL / BN), dim3(256), 0, stream,
                       a1, a2, Ws, bsh, cnt, rowl, out);
  }
}

// Round 10
// 297.590 us; speedup vs baseline: 1.2245x; 1.2245x over previous
//
#include <hip/hip_runtime.h>
#include <hip/hip_fp16.h>
#include <stdint.h>

// ---------------- problem constants ----------------
#define NROWS  16384      // B*S
#define DMODEL 2048
#define DIN    4096
#define NG     (NROWS*3)

// ---------------- workspace layout (bytes) ----------------
#define WS_CNT   0
#define WS_BF    256
#define WS_WF    512                       // W_fused EXPERT-MAJOR [3][4096] f32
#define WS_GUM   65536
#define WS_ROWL  262144                    // 16384 ints (compacted)
#define WS_SEGC2 327680                    // 64 counters, 128B stride (8KB)
#define WS_SEGC1 335872                    // 64 counters, 128B stride (8KB)
#define WS_RSEG  344064                    // 64 x 256 ints segment rowlists (64KB)
#define WS_WH    (1u<<20)                  // W^T fp16 [2048][4096], pre-swizzled
#define WS_ACOMP (WS_WH + (16u<<20))       // A fp16 [16384][4096] by COMPACT idx, pre-swizzled
#define WS_ACOMP_BYTES ((size_t)NROWS * DIN * 2)

typedef __attribute__((ext_vector_type(8))) _Float16 f16x8;
typedef __attribute__((ext_vector_type(4))) float f32x4;

#define THREEFRY_PARTITIONABLE 1

__device__ __forceinline__ void tf2x32(uint32_t k0, uint32_t k1,
                                       uint32_t x0, uint32_t x1,
                                       uint32_t& o0, uint32_t& o1) {
  uint32_t k2 = k0 ^ k1 ^ 0x1BD11BDAu;
  x0 += k0; x1 += k1;
#define TFR(r) { x0 += x1; x1 = (x1 << r) | (x1 >> (32 - r)); x1 ^= x0; }
  TFR(13) TFR(15) TFR(26) TFR(6)
  x0 += k1; x1 += k2 + 1u;
  TFR(17) TFR(29) TFR(16) TFR(24)
  x0 += k2; x1 += k0 + 2u;
  TFR(13) TFR(15) TFR(26) TFR(6)
  x0 += k0; x1 += k1 + 3u;
  TFR(17) TFR(29) TFR(16) TFR(24)
  x0 += k1; x1 += k2 + 4u;
  TFR(13) TFR(15) TFR(26) TFR(6)
  x0 += k2; x1 += k0 + 5u;
#undef TFR
  o0 = x0; o1 = x1;
}

// Gumbel noise + (merged) zeroing of atomic counters: blocks 0-3 zero the
// 16KB segc region (segc2 then segc1, contiguous), block 4 zeros cnt.
// (round-9 replay-proven)
__global__ void k_gumbel(float* __restrict__ g, int* __restrict__ cnt,
                         int* __restrict__ segz) {
  const int t = threadIdx.x;
  if (blockIdx.x < 4) {
    int base = ((int)blockIdx.x << 10) + (t << 2);
#pragma unroll
    for (int i = 0; i < 4; ++i) segz[base + i] = 0;
  } else if (blockIdx.x == 4 && t < 8) {
    cnt[t] = 0;
  }
  int j = blockIdx.x * blockDim.x + t;
  if (j >= NG) return;
  uint32_t b0, b1, bits;
#if THREEFRY_PARTITIONABLE
  tf2x32(0u, 42u, 0u, (uint32_t)j, b0, b1);
  bits = b0 ^ b1;
#else
  const int half = NG / 2;
  if (j < half) { tf2x32(0u, 42u, (uint32_t)j, (uint32_t)(j + half), b0, b1); bits = b0; }
  else          { tf2x32(0u, 42u, (uint32_t)(j - half), (uint32_t)j, b0, b1); bits = b1; }
#endif
  float U = __uint_as_float((bits >> 9) | 0x3f800000u) - 1.0f;
  U = fmaxf(U, 1e-10f);
  U = fminf(U, 1.0f);
  g[j] = -logf(-logf(U));
}

// W_fused (expert-major): Wf[e*4096+k] = sum_d W_share[k][d]*W_router[d][e]
__global__ __launch_bounds__(256)
void k_wfused(const float* __restrict__ Ws, const float* __restrict__ bsh,
              const float* __restrict__ Wr, const float* __restrict__ br,
              float* __restrict__ Wf, float* __restrict__ bf) {
  const int k = blockIdx.x;
  const int t = threadIdx.x;
  const float* src = (k < DIN) ? (Ws + (size_t)k * DMODEL) : bsh;
  float4 x0 = *(const float4*)(src + t * 8);
  float4 x1 = *(const float4*)(src + t * 8 + 4);
  float xv[8] = {x0.x, x0.y, x0.z, x0.w, x1.x, x1.y, x1.z, x1.w};
  float4 w4[6];
  const float4* wp = (const float4*)(Wr + t * 24);
#pragma unroll
  for (int i = 0; i < 6; ++i) w4[i] = wp[i];
  const float* wfv = (const float*)w4;
  float z0 = 0.f, z1 = 0.f, z2 = 0.f;
#pragma unroll
  for (int jj = 0; jj < 8; ++jj) {
    z0 = fmaf(xv[jj], wfv[jj*3+0], z0);
    z1 = fmaf(xv[jj], wfv[jj*3+1], z1);
    z2 = fmaf(xv[jj], wfv[jj*3+2], z2);
  }
#pragma unroll
  for (int off = 32; off > 0; off >>= 1) {
    z0 += __shfl_down(z0, off, 64);
    z1 += __shfl_down(z1, off, 64);
    z2 += __shfl_down(z2, off, 64);
  }
  __shared__ float red[4][3];
  int lane = t & 63, wv = t >> 6;
  if (lane == 0) { red[wv][0] = z0; red[wv][1] = z1; red[wv][2] = z2; }
  __syncthreads();
  if (t == 0) {
    float s0 = red[0][0] + red[1][0] + red[2][0] + red[3][0];
    float s1 = red[0][1] + red[1][1] + red[2][1] + red[3][1];
    float s2 = red[0][2] + red[1][2] + red[2][2] + red[3][2];
    if (k < DIN) { Wf[k] = s0; Wf[4096 + k] = s1; Wf[8192 + k] = s2; }
    else { bf[0] = s0 + br[0]; bf[1] = s1 + br[1]; bf[2] = s2 + br[2]; }
  }
}

// ---------------- fp16 helpers (RNE) ----------------
__device__ __forceinline__ uint16_t f16b(float x) {
  return __half_as_ushort(__float2half(x));
}
__device__ __forceinline__ uint2 pack4h(float4 v) {
  return make_uint2((uint32_t)f16b(v.x) | ((uint32_t)f16b(v.y) << 16),
                    (uint32_t)f16b(v.z) | ((uint32_t)f16b(v.w) << 16));
}

// Transpose W_share [4096][2048] f32 -> Wh [2048][4096] fp16, pre-swizzled by
// n-row (chunk c stored at c ^ (n&7)) so linear global_load_lds yields the
// conflict-free LDS layout (rounds 2-9 proven).
__global__ __launch_bounds__(256)
void k_wsplit(const float* __restrict__ Ws, uint16_t* __restrict__ Wh) {
  const int kt = blockIdx.x;        // 64 k-tiles of 64
  const int nb = blockIdx.y;        // 32 n-tiles of 64
  const int k0 = kt << 6, n0 = nb << 6;
  __shared__ float T[64][65];
  const int t = threadIdx.x;
#pragma unroll
  for (int r = 0; r < 4; ++r) {
    int lin = r * 256 + t;
    int ki = lin >> 4;
    int nj = (lin & 15) << 2;
    float4 v = *(const float4*)(Ws + (size_t)(k0 + ki) * DMODEL + n0 + nj);
    T[ki][nj+0] = v.x; T[ki][nj+1] = v.y; T[ki][nj+2] = v.z; T[ki][nj+3] = v.w;
  }
  __syncthreads();
#pragma unroll
  for (int r = 0; r < 4; ++r) {
    int lin = r * 256 + t;
    int nl = lin >> 4;
    int k4 = (lin & 15) << 2;
    int ng = n0 + nl;
    int c = k4 >> 3, e0 = k4 & 7;
    float x0 = T[k4+0][nl], x1 = T[k4+1][nl], x2 = T[k4+2][nl], x3 = T[k4+3][nl];
    size_t off = ((size_t)ng << 12) + k0 + ((size_t)((c ^ (ng & 7)) << 3)) + e0;
    *(uint2*)(Wh + off) = make_uint2((uint32_t)f16b(x0) | ((uint32_t)f16b(x1) << 16),
                                     (uint32_t)f16b(x2) | ((uint32_t)f16b(x3) << 16));
  }
}

// Router: wave-per-row, weights streamed from L2, segment-local atomics
// (rounds 6-9 proven, unchanged).
__global__ __launch_bounds__(256)
void k_router(const float* __restrict__ a1, const float* __restrict__ a2,
              const float* __restrict__ Wf, const float* __restrict__ bf,
              const float* __restrict__ gum, float* __restrict__ out,
              int* __restrict__ segc1, int* __restrict__ segc2,
              int* __restrict__ rowl_seg) {
  const int t = threadIdx.x;
  const int lane = t & 63, w = t >> 6;
  const int row = (int)blockIdx.x * 4 + w;
  const float* pa = a1 + ((size_t)row << 11) + (lane << 2);
  const float* pb = a2 + ((size_t)row << 11) + (lane << 2);
  const float* w0 = Wf + (lane << 2);
  const float* w1 = Wf + 4096 + (lane << 2);
  const float* w2 = Wf + 8192 + (lane << 2);
  float z0 = 0.f, z1 = 0.f, z2 = 0.f;
#pragma unroll
  for (int c = 0; c < 8; ++c) {
    const int k = c << 8;
    float4 a = *(const float4*)(pa + k);
    float4 u0 = *(const float4*)(w0 + k);
    float4 u1 = *(const float4*)(w1 + k);
    float4 u2 = *(const float4*)(w2 + k);
    z0 = fmaf(a.x,u0.x,fmaf(a.y,u0.y,fmaf(a.z,u0.z,fmaf(a.w,u0.w,z0))));
    z1 = fmaf(a.x,u1.x,fmaf(a.y,u1.y,fmaf(a.z,u1.z,fmaf(a.w,u1.w,z1))));
    z2 = fmaf(a.x,u2.x,fmaf(a.y,u2.y,fmaf(a.z,u2.z,fmaf(a.w,u2.w,z2))));
    float4 b = *(const float4*)(pb + k);
    float4 v0 = *(const float4*)(w0 + 2048 + k);
    float4 v1 = *(const float4*)(w1 + 2048 + k);
    float4 v2 = *(const float4*)(w2 + 2048 + k);
    z0 = fmaf(b.x,v0.x,fmaf(b.y,v0.y,fmaf(b.z,v0.z,fmaf(b.w,v0.w,z0))));
    z1 = fmaf(b.x,v1.x,fmaf(b.y,v1.y,fmaf(b.z,v1.z,fmaf(b.w,v1.w,z1))));
    z2 = fmaf(b.x,v2.x,fmaf(b.y,v2.y,fmaf(b.z,v2.z,fmaf(b.w,v2.w,z2))));
  }
  // butterfly reduce (commutative per stage -> bitwise identical on all lanes)
#pragma unroll
  for (int m = 1; m < 64; m <<= 1) {
    z0 += __shfl_xor(z0, m, 64);
    z1 += __shfl_xor(z1, m, 64);
    z2 += __shfl_xor(z2, m, 64);
  }
  const float l0 = z0 + bf[0] + gum[row*3+0];
  const float l1 = z1 + bf[1] + gum[row*3+1];
  const float l2 = z2 + bf[2] + gum[row*3+2];
  int idx = 0; float m = l0;
  if (l1 > m) { m = l1; idx = 1; }
  if (l2 > m) { idx = 2; }

  if (lane == 0) {
    const int seg = row >> 8;
    if (idx == 1) {
      atomicAdd(segc1 + (seg << 5), 1);
    } else if (idx == 2) {
      int p = atomicAdd(segc2 + (seg << 5), 1);
      rowl_seg[(seg << 8) + p] = row;
    }
  }
  if (idx < 2) {
    const float* src = (idx == 0) ? pa : pb;
    float* po = out + ((size_t)row << 11) + (lane << 2);
#pragma unroll
    for (int c = 0; c < 8; ++c)
      *(float4*)(po + (c << 8)) = *(const float4*)(src + (c << 8));
  }
}

// Compact 64 segment lists -> rowl[0..M) + cnt[0..2]; (merged) losses.
// (round-9 replay-proven)
__global__ __launch_bounds__(256)
void k_fixup(const int* __restrict__ segc1, const int* __restrict__ segc2,
             const int* __restrict__ rowl_seg, int* __restrict__ cnt,
             int* __restrict__ rowl, float* __restrict__ losses) {
  __shared__ int scnt[64], sstart[64];
  const int t = threadIdx.x;
  if (t < 64) scnt[t] = segc2[t << 5];
  __syncthreads();
  if (t == 0) {
    int acc = 0, s1 = 0;
#pragma unroll
    for (int g = 0; g < 64; ++g) { sstart[g] = acc; acc += scnt[g]; }
#pragma unroll
    for (int g = 0; g < 64; ++g) s1 += segc1[g << 5];
    cnt[2] = acc; cnt[1] = s1; cnt[0] = NROWS - acc - s1;
    // losses: p is exactly one-hot => entropy term exactly 0
    const float inv = 1.0f / (float)NROWS;
    float m0 = (float)(NROWS - acc - s1) * inv;
    float m1 = (float)s1 * inv;
    float m2 = (float)acc * inv;
    float lb = -(m0 * logf(m0 + 1e-8f) + m1 * logf(m1 + 1e-8f)
               + m2 * logf(m2 + 1e-8f));
    losses[0] = 0.0f;
    losses[1] = lb;
  }
  __syncthreads();
  for (int g = 0; g < 64; ++g) {
    int c = scnt[g], base = sstart[g];
    for (int i = t; i < c; i += 256) rowl[base + i] = rowl_seg[(g << 8) + i];
  }
}

// Compaction: Acomp[i] <- fp16(combined[rowl[i]]) pre-swizzled (rounds 7-9 proven).
__global__ __launch_bounds__(256)
void k_acomp(const float* __restrict__ a1, const float* __restrict__ a2,
             const int* __restrict__ cnt, const int* __restrict__ rowl,
             uint16_t* __restrict__ acomp) {
  const int t = threadIdx.x;
  const int lane = t & 63, w = t >> 6;
  const int i = (int)blockIdx.x * 4 + w;    // compact index
  if (i >= cnt[2]) return;
  const int row = rowl[i];
  const int psw = i & 7;
  uint16_t* ar = acomp + ((size_t)i << 12);
  const float* pa = a1 + ((size_t)row << 11);
  const float* pb = a2 + ((size_t)row << 11);
#pragma unroll
  for (int it = 0; it < 8; ++it) {
    int e = (it << 8) + (lane << 2);        // element index 0..2047
    float4 va = *(const float4*)(pa + e);
    float4 vb = *(const float4*)(pb + e);
    int g = e >> 6, c = (e >> 3) & 7, o = e & 7;
    int d = (g << 6) + ((c ^ psw) << 3) + o;
    *(uint2*)(ar + d) = pack4h(va);
    *(uint2*)(ar + 2048 + d) = pack4h(vb);
  }
}

// Single-product fp16 MFMA GEMM over selected rows (ROUND-8 KERNEL, verbatim —
// the 132 µs configuration; round-9's BN=64 regressed to 195 µs on A-refetch
// traffic): 128x128 tile, BK=64, 4 waves (2x2), mfma_f32_16x16x32_f16.
// AMODE 0: A staged via global_load_lds from compacted pre-swizzled Acomp.
// AMODE 1: A gathered from a1/a2 fp32 + in-kernel convert (small-ws fallback).
template<int AMODE>
__global__ __launch_bounds__(256, 4)
void k_gemm_fp16(const float* __restrict__ a1, const float* __restrict__ a2,
                 const uint16_t* __restrict__ Acomp,
                 const uint16_t* __restrict__ Wh,
                 const float* __restrict__ bsh, const int* __restrict__ cnt,
                 const int* __restrict__ rowl, float* __restrict__ out) {
  const int M = cnt[2];
  const int nwg = (int)gridDim.x;
  const int mTiles = nwg >> 4;
  // m204 bijective XCD remap, bm-major decode (XCD chunk shares bn panels)
  int xcd = blockIdx.x & 7, rest = blockIdx.x >> 3;
  int q = nwg >> 3, r = nwg & 7;
  int swz = (xcd < r ? xcd * (q + 1) : r * (q + 1) + (xcd - r) * q) + rest;
  const int bm = swz % mTiles;
  const int bn = swz / mTiles;
  if (bm * 128 >= M) return;
  const int n0 = bn << 7;

  __shared__ uint16_t AS[128 * 64];
  __shared__ uint16_t BhS[128 * 64];
  __shared__ int rows[128];
  const int t = threadIdx.x;
  const int lane = t & 63, w = t >> 6;
  const int wm = w >> 1, wn = w & 1;
  if (t < 128) { int i = bm * 128 + t; rows[t] = (i < M) ? rowl[i] : -1; }
  __syncthreads();

  f32x4 acc[4][4];
#pragma unroll
  for (int fm = 0; fm < 4; ++fm)
#pragma unroll
    for (int fn = 0; fn < 4; ++fn) acc[fm][fn] = (f32x4){0.f, 0.f, 0.f, 0.f};
  float bias[4];
#pragma unroll
  for (int fn = 0; fn < 4; ++fn)
    bias[fn] = bsh[n0 + (wn << 6) + (fn << 4) + (lane & 15)];

  const size_t arow0 = ((size_t)(bm << 7)) << 12;   // (bm*128)*4096 elems

  for (int kt = 0; kt < 64; ++kt) {
    __syncthreads();                 // prior iter's LDS reads done
    // ---- B stage: Wh via global_load_lds, linear dest (src pre-swizzled)
#pragma unroll
    for (int i = 0; i < 4; ++i) {
      int idx = (w << 8) + (i << 6) + lane;
      int nrow = idx >> 3, c = idx & 7;
      size_t goff = ((size_t)(n0 + nrow) << 12) + (kt << 6) + (c << 3);
      __builtin_amdgcn_global_load_lds(
          (const __attribute__((address_space(1))) void*)(Wh + goff),
          (__attribute__((address_space(3))) void*)((char*)BhS + (w << 12) + (i << 10)),
          16, 0, 0);
    }
    // ---- A stage
    if (AMODE == 0) {
#pragma unroll
      for (int i = 0; i < 4; ++i) {
        int idx = (w << 8) + (i << 6) + lane;
        int m = idx >> 3, c = idx & 7;
        const uint16_t* src = Acomp + arow0 + (((size_t)m) << 12) + (kt << 6) + (c << 3);
        __builtin_amdgcn_global_load_lds(
            (const __attribute__((address_space(1))) void*)src,
            (__attribute__((address_space(3))) void*)((char*)AS + (w << 12) + (i << 10)),
            16, 0, 0);
      }
    } else {
#pragma unroll
      for (int i = 0; i < 4; ++i) {
        int idx = t + (i << 8);
        int m = idx >> 3, c = idx & 7;
        int row = rows[m];
        float4 v0 = make_float4(0.f,0.f,0.f,0.f), v1 = v0;
        if (row >= 0) {
          const float* s = (kt < 32)
              ? (a1 + (size_t)row * DMODEL + (kt << 6) + (c << 3))
              : (a2 + (size_t)row * DMODEL + ((kt - 32) << 6) + (c << 3));
          v0 = *(const float4*)s; v1 = *(const float4*)(s + 4);
        }
        uint32_t q0 = (uint32_t)f16b(v0.x) | ((uint32_t)f16b(v0.y) << 16);
        uint32_t q1 = (uint32_t)f16b(v0.z) | ((uint32_t)f16b(v0.w) << 16);
        uint32_t q2 = (uint32_t)f16b(v1.x) | ((uint32_t)f16b(v1.y) << 16);
        uint32_t q3 = (uint32_t)f16b(v1.z) | ((uint32_t)f16b(v1.w) << 16);
        *(uint4*)((char*)AS + m * 128 + ((c ^ (m & 7)) << 4)) = make_uint4(q0, q1, q2, q3);
      }
    }
    __syncthreads();                 // drain vmcnt (gload_lds) + lgkm (ds_write)
    // ---- compute: 2 k-slices x 4x4 frags x 1 product
#pragma unroll
    for (int ks = 0; ks < 2; ++ks) {
      const int chb = (ks << 2) | (lane >> 4);
      f16x8 af[4];
#pragma unroll
      for (int fm = 0; fm < 4; ++fm) {
        int rm = (wm << 6) + (fm << 4) + (lane & 15);
        af[fm] = *(const f16x8*)((const char*)AS + rm * 128 + ((chb ^ (rm & 7)) << 4));
      }
#pragma unroll
      for (int fn = 0; fn < 4; ++fn) {
        int rn = (wn << 6) + (fn << 4) + (lane & 15);
        int sw = (chb ^ (rn & 7)) << 4;
        f16x8 bh = *(const f16x8*)((const char*)BhS + rn * 128 + sw);
#pragma unroll
        for (int fm = 0; fm < 4; ++fm)
          acc[fm][fn] = __builtin_amdgcn_mfma_f32_16x16x32_f16(af[fm], bh, acc[fm][fn], 0, 0, 0);
      }
    }
  }
  // epilogue: C/D layout col=lane&15, row=(lane>>4)*4+j
#pragma unroll
  for (int fm = 0; fm < 4; ++fm) {
    int rbase = (wm << 6) + (fm << 4) + ((lane >> 4) << 2);
#pragma unroll
    for (int j = 0; j < 4; ++j) {
      int row = rows[rbase + j];
      if (row < 0) continue;
      float* po = out + (size_t)row * DMODEL + n0 + (wn << 6) + (lane & 15);
#pragma unroll
      for (int fn = 0; fn < 4; ++fn)
        po[fn << 4] = acc[fm][fn][j] + bias[fn];
    }
  }
}

// fp32 fallback GEMM (only if ws too small for Wh)
#define BM 128
#define BN 128
#define BK 32
__global__ __launch_bounds__(256)
void k_gemm_f32(const float* __restrict__ a1, const float* __restrict__ a2,
                const float* __restrict__ Ws, const float* __restrict__ bsh,
                const int* __restrict__ cnt, const int* __restrict__ rowl,
                float* __restrict__ out) {
  const int M = cnt[2];
  const int bm = blockIdx.x;
  if (bm * BM >= M) return;
  const int bn = blockIdx.y;
  __shared__ float As[BK][132];
  __shared__ float Bs[BK][128];
  __shared__ int rows[BM];
  const int t = threadIdx.x;
  if (t < BM) {
    int i = bm * BM + t;
    rows[t] = (i < M) ? rowl[i] : -1;
  }
  __syncthreads();
  float acc[8][8];
#pragma unroll
  for (int i = 0; i < 8; ++i)
#pragma unroll
    for (int j = 0; j < 8; ++j) acc[i][j] = 0.f;
  const int tx = t & 15, ty = t >> 4;
  for (int k0 = 0; k0 < DIN; k0 += BK) {
    const float* Abase = (k0 < DMODEL) ? a1 : a2;
    const int kb = (k0 < DMODEL) ? k0 : (k0 - DMODEL);
    float4 av[4], bv4[4];
#pragma unroll
    for (int r = 0; r < 4; ++r) {
      int lin = r * 256 + t;
      int mi = lin >> 3;
      int ki = (lin & 7) << 2;
      int row = rows[mi];
      av[r] = (row >= 0) ? *(const float4*)(Abase + (size_t)row * DMODEL + kb + ki)
                         : make_float4(0.f, 0.f, 0.f, 0.f);
    }
#pragma unroll
    for (int r = 0; r < 4; ++r) {
      int lin = r * 256 + t;
      int ki = lin >> 5;
      int ni = (lin & 31) << 2;
      bv4[r] = *(const float4*)(Ws + (size_t)(k0 + ki) * DMODEL + bn * BN + ni);
    }
    __syncthreads();
#pragma unroll
    for (int r = 0; r < 4; ++r) {
      int lin = r * 256 + t;
      int mi = lin >> 3;
      int ki = (lin & 7) << 2;
      As[ki + 0][mi] = av[r].x;
      As[ki + 1][mi] = av[r].y;
      As[ki + 2][mi] = av[r].z;
      As[ki + 3][mi] = av[r].w;
      int k2 = lin >> 5;
      int ni = (lin & 31) << 2;
      *(float4*)(&Bs[k2][ni]) = bv4[r];
    }
    __syncthreads();
#pragma unroll
    for (int kk = 0; kk < BK; ++kk) {
      float4 aL = *(const float4*)(&As[kk][ty << 2]);
      float4 aH = *(const float4*)(&As[kk][64 + (ty << 2)]);
      float4 bL = *(const float4*)(&Bs[kk][tx << 2]);
      float4 bH = *(const float4*)(&Bs[kk][64 + (tx << 2)]);
      float am[8] = {aL.x, aL.y, aL.z, aL.w, aH.x, aH.y, aH.z, aH.w};
      float bb[8] = {bL.x, bL.y, bL.z, bL.w, bH.x, bH.y, bH.z, bH.w};
#pragma unroll
      for (int i = 0; i < 8; ++i)
#pragma unroll
        for (int j = 0; j < 8; ++j)
          acc[i][j] = fmaf(am[i], bb[j], acc[i][j]);
    }
  }
  float bias[8];
#pragma unroll
  for (int j = 0; j < 4; ++j) {
    bias[j]     = bsh[bn * BN + (tx << 2) + j];
    bias[4 + j] = bsh[bn * BN + 64 + (tx << 2) + j];
  }
#pragma unroll
  for (int i = 0; i < 8; ++i) {
    int m = (i < 4) ? ((ty << 2) + i) : (64 + (ty << 2) + (i - 4));
    int row = rows[m];
    if (row < 0) continue;
    float* po = out + (size_t)row * DMODEL + bn * BN;
    float4 v0 = make_float4(acc[i][0] + bias[0], acc[i][1] + bias[1],
                            acc[i][2] + bias[2], acc[i][3] + bias[3]);
    float4 v1 = make_float4(acc[i][4] + bias[4], acc[i][5] + bias[5],
                            acc[i][6] + bias[6], acc[i][7] + bias[7]);
    *(float4*)(po + (tx << 2)) = v0;
    *(float4*)(po + 64 + (tx << 2)) = v1;
  }
}

extern "C" void kernel_launch(void* const* d_in, const int* in_sizes, int n_in,
                              void* d_out, int out_size, void* d_ws, size_t ws_size,
                              hipStream_t stream) {
  const float* a1  = (const float*)d_in[0];
  const float* a2  = (const float*)d_in[1];
  const float* Ws  = (const float*)d_in[2];
  const float* bsh = (const float*)d_in[3];
  const float* Wr  = (const float*)d_in[4];
  const float* br  = (const float*)d_in[5];
  float* out = (float*)d_out;
  char* ws = (char*)d_ws;
  int*      cnt   = (int*)(ws + WS_CNT);
  float*    bf    = (float*)(ws + WS_BF);
  float*    Wf    = (float*)(ws + WS_WF);
  float*    gum   = (float*)(ws + WS_GUM);
  int*      rowl  = (int*)(ws + WS_ROWL);
  int*      segc2 = (int*)(ws + WS_SEGC2);
  int*      segc1 = (int*)(ws + WS_SEGC1);
  int*      rseg  = (int*)(ws + WS_RSEG);
  uint16_t* Wh    = (uint16_t*)(ws + WS_WH);
  uint16_t* Acomp = (uint16_t*)(ws + WS_ACOMP);
  float* losses = out + (size_t)NROWS * DMODEL;

  const bool fp16path = ws_size >= (size_t)WS_ACOMP;
  const bool fullA = ws_size >= (size_t)WS_ACOMP + WS_ACOMP_BYTES;

  hipLaunchKernelGGL(k_gumbel, dim3((NG + 255)/256), dim3(256), 0, stream, gum, cnt, segc2);
  hipLaunchKernelGGL(k_wfused, dim3(DIN + 1),        dim3(256), 0, stream, Ws, bsh, Wr, br, Wf, bf);
  if (fp16path) {
    hipLaunchKernelGGL(k_wsplit, dim3(64, 32),       dim3(256), 0, stream, Ws, Wh);
    hipLaunchKernelGGL(k_router, dim3(NROWS / 4),    dim3(256), 0, stream,
                       a1, a2, Wf, bf, gum, out, segc1, segc2, rseg);
    hipLaunchKernelGGL(k_fixup,  dim3(1),            dim3(256), 0, stream,
                       segc1, segc2, rseg, cnt, rowl, losses);
    if (fullA) {
      hipLaunchKernelGGL(k_acomp, dim3(NROWS / 4),   dim3(256), 0, stream,
                         a1, a2, cnt, rowl, Acomp);
      hipLaunchKernelGGL((k_gemm_fp16<0>), dim3((NROWS / 128) * 16), dim3(256), 0, stream,
                         a1, a2, Acomp, Wh, bsh, cnt, rowl, out);
    } else {
      hipLaunchKernelGGL((k_gemm_fp16<1>), dim3((NROWS / 128) * 16), dim3(256), 0, stream,
                         a1, a2, Acomp, Wh, bsh, cnt, rowl, out);
    }
  } else {
    hipLaunchKernelGGL(k_router, dim3(NROWS / 4),    dim3(256), 0, stream,
                       a1, a2, Wf, bf, gum, out, segc1, segc2, rseg);
    hipLaunchKernelGGL(k_fixup,  dim3(1),            dim3(256), 0, stream,
                       segc1, segc2, rseg, cnt, rowl, losses);
    hipLaunchKernelGGL(k_gemm_f32, dim3(NROWS / BM, DMODEL / BN), dim3(256), 0, stream,
                       a1, a2, Ws, bsh, cnt, rowl, out);
  }
}